// Round 9
// baseline (370.062 us; speedup 1.0000x reference)
//
#include <hip/hip_runtime.h>
#include <hip/hip_bf16.h>

typedef __attribute__((ext_vector_type(8))) short short8;
typedef __attribute__((ext_vector_type(4))) float f32x4;
typedef __attribute__((ext_vector_type(4))) unsigned int uint32x4;

__device__ __forceinline__ unsigned short f2bf(float v) {
    __hip_bfloat16 h = __float2bfloat16(v);   // RNE
    return *reinterpret_cast<unsigned short*>(&h);
}
__device__ __forceinline__ float bf2f(unsigned short u) {
    union { unsigned int i; float f; } x;
    x.i = (unsigned int)u << 16;
    return x.f;
}

constexpr int MAXB  = 2048;   // max fine buckets (N/64 = 1563 here)
constexpr int MAXPB = 1792;   // padded slots per bucket (mean 1024, sigma 32 -> 24 sigma)

// ---------------------------------------------------------------------------
// Weight pre-transpose: Wt[(r*H + h)*64 + d] = bf16( r<R ? W[r][d][h]
//                                                        : Wself[d][h] ).
// ---------------------------------------------------------------------------
template<int H>
__global__ __launch_bounds__(256) void transpose_w(
    const float* __restrict__ W, const float* __restrict__ Wself,
    unsigned short* __restrict__ Wt, int R)
{
    int i = blockIdx.x * 256 + threadIdx.x;
    int total = (R + 1) * H * 64;
    if (i >= total) return;
    int d = i & 63;
    int hh = i >> 6;               // r*H + h
    int r = hh / H, h = hh % H;    // H compile-time -> shifts
    float v = (r < R) ? W[((size_t)r * 64 + d) * H + h]
                      : Wself[(size_t)d * H + h];
    Wt[i] = f2bf(v);
}

// ---------------------------------------------------------------------------
// Cast feat fp32 -> bf16 rows. 8 elems/thread.
// ---------------------------------------------------------------------------
__global__ __launch_bounds__(256) void cast_bf16x8(
    const float* __restrict__ in, unsigned short* __restrict__ outp, int n8)
{
    int i = blockIdx.x * 256 + threadIdx.x;
    if (i >= n8) return;
    const float4 a = ((const float4*)in)[(size_t)i * 2];
    const float4 b = ((const float4*)in)[(size_t)i * 2 + 1];
    short8 u;
    u[0] = (short)f2bf(a.x); u[1] = (short)f2bf(a.y);
    u[2] = (short)f2bf(a.z); u[3] = (short)f2bf(a.w);
    u[4] = (short)f2bf(b.x); u[5] = (short)f2bf(b.y);
    u[6] = (short)f2bf(b.z); u[7] = (short)f2bf(b.w);
    *(short8*)&outp[(size_t)i * 8] = u;
}

// ---------------------------------------------------------------------------
// Padded bucket partition (single pass; R8-verified structure).
// Record: (src << 9) | (et << 6) | (dst & 63).  (src < 2^17, et < 8)
// ---------------------------------------------------------------------------
__global__ __launch_bounds__(256) void zero_int(int* __restrict__ p, int n) {
    int i = blockIdx.x * 256 + threadIdx.x;
    if (i < n) p[i] = 0;
}

__global__ __launch_bounds__(256) void partition_pad(
    const int* __restrict__ src, const int* __restrict__ dst,
    const int* __restrict__ et, int* __restrict__ gcnt,
    int* __restrict__ rec, int E, int N, int B, int CH)
{
    __shared__ int cnt[MAXB];
    __shared__ int base[MAXB];
    const int t = threadIdx.x;
    const int e0 = blockIdx.x * CH, e1 = min(E, e0 + CH);

    for (int i = t; i < B; i += 256) cnt[i] = 0;
    __syncthreads();
    for (int e = e0 + t; e < e1; e += 256) atomicAdd(&cnt[dst[e] >> 6], 1);
    __syncthreads();
    for (int i = t; i < B; i += 256) {
        int h = cnt[i];
        base[i] = h ? atomicAdd(&gcnt[i], h) : 0;
        cnt[i] = 0;
    }
    __syncthreads();
    for (int e = e0 + t; e < e1; e += 256) {
        int d = dst[e];
        int b = d >> 6;
        int pos = base[b] + atomicAdd(&cnt[b], 1);
        if (pos < MAXPB)
            rec[(size_t)b * MAXPB + pos] = (src[e] << 9) | (et[e] << 6) | (d & 63);
    }
}

// ---------------------------------------------------------------------------
// Per-bucket 64*R-bin counting sort by (dst-local, rel).
// nrpS/nrpE[b*64R + local*R + r] = range into padded eidx; eidx[pos] = src.
// ---------------------------------------------------------------------------
__global__ __launch_bounds__(256) void bucket_sort9(
    const int* __restrict__ gcnt, const int* __restrict__ rec,
    int* __restrict__ eidx, int* __restrict__ nrpS, int* __restrict__ nrpE,
    int R)
{
    __shared__ int hist[512];
    __shared__ int excl[512];
    __shared__ int cur[512];
    __shared__ int ts[256];
    const int b = blockIdx.x;
    const int tid = threadIdx.x;
    const int NB = 64 * R;                 // <= 512
    const int p0 = b * MAXPB;
    const int ne = min(gcnt[b], MAXPB);

    for (int i = tid; i < NB; i += 256) hist[i] = 0;
    __syncthreads();
    for (int p = tid; p < ne; p += 256) {
        int rv = rec[p0 + p];
        atomicAdd(&hist[(rv & 63) * R + ((rv >> 6) & 7)], 1);
    }
    __syncthreads();
    // block scan of NB bins (PER <= 2 per thread)
    const int PER = (NB + 255) / 256;
    int loc[2] = {0, 0};
    int s = 0;
    for (int j = 0; j < PER; ++j) {
        int i = tid * PER + j;
        loc[j] = (i < NB) ? hist[i] : 0;
        s += loc[j];
    }
    ts[tid] = s;
    __syncthreads();
    for (int off = 1; off < 256; off <<= 1) {
        int x = (tid >= off) ? ts[tid - off] : 0;
        __syncthreads();
        ts[tid] += x;
        __syncthreads();
    }
    int run = ts[tid] - s;
    for (int j = 0; j < PER; ++j) {
        int i = tid * PER + j;
        if (i < NB) excl[i] = run;
        run += loc[j];
    }
    __syncthreads();
    for (int i = tid; i < NB; i += 256) {
        cur[i] = excl[i];
        nrpS[(size_t)b * NB + i] = p0 + excl[i];
        nrpE[(size_t)b * NB + i] = p0 + excl[i] + hist[i];
    }
    __syncthreads();
    for (int p = tid; p < ne; p += 256) {
        int rv = rec[p0 + p];
        int bin = (rv & 63) * R + ((rv >> 6) & 7);
        int pos = p0 + atomicAdd(&cur[bin], 1);
        eidx[pos] = rv >> 9;   // src
    }
}

// ---------------------------------------------------------------------------
// Register-fused aggregate -> MFMA layer. Block = 1 bucket (64 dst), 4 waves
// x 16 nodes. Lane quad*16+m owns node m's cols [quad*8,+8) and [32+quad*8,+8)
// -- identical to the verified MFMA B-fragment layout, so the per-(node,rel)
// register aggregate converts to the MFMA operand with ZERO shuffles.
// Per rel: 4-lane group walks node's rel-r edges (16B slice each, coalesced
// 128B row), fp32 register accumulate (agg64-proven pattern), convert, MFMA
// against Wt (verified wptr formula). Self term + bias (+relu) in epilogue,
// LDS-staged coalesced 16B writes (verified pattern). No hW materialization.
// ---------------------------------------------------------------------------
template<int HOUT, bool BF16OUT>
__global__ __launch_bounds__(256) void fused_mfma(
    const unsigned short* __restrict__ inb,   // bf16 rows [N][64] (L2-resident)
    const unsigned short* __restrict__ Wt,    // [(R+1)*HOUT][64] bf16
    const float* __restrict__ bias,           // [HOUT]
    const int* __restrict__ nrpS, const int* __restrict__ nrpE,
    const int* __restrict__ eidx,             // src, (bucket,node,rel)-sorted
    void* __restrict__ outp,
    int N, int R)
{
    constexpr int NT = HOUT / 16;             // 4 (H=64) or 2 (H=32)
    constexpr int CPB = 72;                   // bf16 stage stride (144B rows, 2-way)
    alignas(16) __shared__ float Csf[64 * 36];  // 9216B stage
    const int tid = threadIdx.x, b = blockIdx.x;
    const int w = tid >> 6, lane = tid & 63;
    const int m = lane & 15, quad = lane >> 4;
    const int nl = w * 16 + m;                // node local (0..63)
    const int node = b * 64 + nl;
    const int NB = 64 * R;
    const unsigned int* in32 = (const unsigned int*)inb;

    f32x4 acc[NT];
    #pragma unroll
    for (int nt = 0; nt < NT; ++nt) acc[nt] = (f32x4){0.f, 0.f, 0.f, 0.f};

    for (int r = 0; r < R; ++r) {
        const int bin = b * NB + nl * R + r;
        int p = nrpS[bin];
        const int pe = nrpE[bin];

        float a0[8] = {0.f,0.f,0.f,0.f,0.f,0.f,0.f,0.f};
        float a1[8] = {0.f,0.f,0.f,0.f,0.f,0.f,0.f,0.f};
        for (; p + 1 < pe; p += 2) {          // 2-deep unroll for MLP
            int sA = eidx[p], sB = eidx[p + 1];
            uint32x4 loA = *(const uint32x4*)&in32[(size_t)sA * 32 + quad * 4];
            uint32x4 hiA = *(const uint32x4*)&in32[(size_t)sA * 32 + 16 + quad * 4];
            uint32x4 loB = *(const uint32x4*)&in32[(size_t)sB * 32 + quad * 4];
            uint32x4 hiB = *(const uint32x4*)&in32[(size_t)sB * 32 + 16 + quad * 4];
            #pragma unroll
            for (int j = 0; j < 4; ++j) {
                a0[2*j]   += bf2f((unsigned short)(loA[j] & 0xffff));
                a0[2*j+1] += bf2f((unsigned short)(loA[j] >> 16));
                a1[2*j]   += bf2f((unsigned short)(hiA[j] & 0xffff));
                a1[2*j+1] += bf2f((unsigned short)(hiA[j] >> 16));
                a0[2*j]   += bf2f((unsigned short)(loB[j] & 0xffff));
                a0[2*j+1] += bf2f((unsigned short)(loB[j] >> 16));
                a1[2*j]   += bf2f((unsigned short)(hiB[j] & 0xffff));
                a1[2*j+1] += bf2f((unsigned short)(hiB[j] >> 16));
            }
        }
        if (p < pe) {
            int sA = eidx[p];
            uint32x4 loA = *(const uint32x4*)&in32[(size_t)sA * 32 + quad * 4];
            uint32x4 hiA = *(const uint32x4*)&in32[(size_t)sA * 32 + 16 + quad * 4];
            #pragma unroll
            for (int j = 0; j < 4; ++j) {
                a0[2*j]   += bf2f((unsigned short)(loA[j] & 0xffff));
                a0[2*j+1] += bf2f((unsigned short)(loA[j] >> 16));
                a1[2*j]   += bf2f((unsigned short)(hiA[j] & 0xffff));
                a1[2*j+1] += bf2f((unsigned short)(hiA[j] >> 16));
            }
        }

        short8 f0, f1;                        // aggregate == B-fragment layout
        #pragma unroll
        for (int j = 0; j < 8; ++j) { f0[j] = (short)f2bf(a0[j]); f1[j] = (short)f2bf(a1[j]); }

        #pragma unroll
        for (int nt = 0; nt < NT; ++nt) {
            const short8 wf0 = *(const short8*)&Wt[((size_t)(r * HOUT + nt * 16 + m)) * 64 + quad * 8];
            const short8 wf1 = *(const short8*)&Wt[((size_t)(r * HOUT + nt * 16 + m)) * 64 + 32 + quad * 8];
            acc[nt] = __builtin_amdgcn_mfma_f32_16x16x32_bf16(wf0, f0, acc[nt], 0, 0, 0);
            acc[nt] = __builtin_amdgcn_mfma_f32_16x16x32_bf16(wf1, f1, acc[nt], 0, 0, 0);
        }
    }

    // self term: node's own row is already bf16 in memory == fragment directly
    short8 se0 = {}, se1 = {};
    if (node < N) {
        se0 = *(const short8*)&inb[(size_t)node * 64 + quad * 8];
        se1 = *(const short8*)&inb[(size_t)node * 64 + 32 + quad * 8];
    }
    #pragma unroll
    for (int nt = 0; nt < NT; ++nt) {
        const short8 wsf0 = *(const short8*)&Wt[((size_t)(R * HOUT + nt * 16 + m)) * 64 + quad * 8];
        const short8 wsf1 = *(const short8*)&Wt[((size_t)(R * HOUT + nt * 16 + m)) * 64 + 32 + quad * 8];
        acc[nt] = __builtin_amdgcn_mfma_f32_16x16x32_bf16(wsf0, se0, acc[nt], 0, 0, 0);
        acc[nt] = __builtin_amdgcn_mfma_f32_16x16x32_bf16(wsf1, se1, acc[nt], 0, 0, 0);
    }

    // epilogue: bias (+relu for layer1), stage, coalesced 16B writes.
    // D layout (verified): reg i -> h-col = nt*16 + quad*4 + i; lane&15 -> node.
    if constexpr (BF16OUT) {
        unsigned short* Cb = (unsigned short*)Csf;
        #pragma unroll
        for (int nt = 0; nt < NT; ++nt) {
            int col = nt * 16 + quad * 4;
            const float4 bv = *(const float4*)&bias[col];
            ushort4 u;
            u.x = f2bf(fmaxf(acc[nt][0] + bv.x, 0.f));
            u.y = f2bf(fmaxf(acc[nt][1] + bv.y, 0.f));
            u.z = f2bf(fmaxf(acc[nt][2] + bv.z, 0.f));
            u.w = f2bf(fmaxf(acc[nt][3] + bv.w, 0.f));
            *(ushort4*)&Cb[nl * CPB + col] = u;
        }
        __syncthreads();
        unsigned short* outu = (unsigned short*)outp;
        #pragma unroll
        for (int it = 0; it < 2; ++it) {
            int i = tid + it * 256;           // 64 rows x 8 chunks of 16B
            int rw = i >> 3, ch = i & 7;
            int gn = b * 64 + rw;
            if (gn < N) {
                uint32x4 v = *(const uint32x4*)&Cb[rw * CPB + ch * 8];
                *(uint32x4*)&outu[(size_t)gn * 64 + ch * 8] = v;
            }
        }
    } else {
        float* Cf = Csf;
        #pragma unroll
        for (int nt = 0; nt < NT; ++nt) {
            int col = nt * 16 + quad * 4;
            const float4 bv = *(const float4*)&bias[col];
            float4 o = make_float4(acc[nt][0] + bv.x, acc[nt][1] + bv.y,
                                   acc[nt][2] + bv.z, acc[nt][3] + bv.w);
            *(float4*)&Cf[nl * 36 + col] = o;
        }
        __syncthreads();
        float* outf = (float*)outp;
        #pragma unroll
        for (int it = 0; it < 2; ++it) {
            int i = tid + it * 256;           // 64 rows x 8 float4
            int rw = i >> 3, ch = i & 7;
            int gn = b * 64 + rw;
            if (gn < N) {
                float4 v = *(const float4*)&Cf[rw * 36 + ch * 4];
                *(float4*)&outf[(size_t)gn * 32 + ch * 4] = v;
            }
        }
    }
}

extern "C" void kernel_launch(void* const* d_in, const int* in_sizes, int n_in,
                              void* d_out, int out_size, void* d_ws, size_t ws_size,
                              hipStream_t stream)
{
    const float* feat = (const float*)d_in[0];
    const int*   src  = (const int*)d_in[1];
    const int*   dst  = (const int*)d_in[2];
    const int*   et   = (const int*)d_in[3];
    const float* W1   = (const float*)d_in[4];
    const float* Ws1  = (const float*)d_in[5];
    const float* b1   = (const float*)d_in[6];
    const float* W2   = (const float*)d_in[7];
    const float* Ws2  = (const float*)d_in[8];
    const float* b2   = (const float*)d_in[9];
    float* out = (float*)d_out;

    const int N = in_sizes[0] / 64;           // 100000
    const int E = in_sizes[1];                // 1600000
    const int R = in_sizes[4] / (64 * 64);    // 8
    const int B = (N + 63) / 64;              // 1563 fine buckets

    // Workspace layout
    unsigned short* fstage = (unsigned short*)d_ws;            // [N][64] bf16 feat
    unsigned short* h1     = fstage + (size_t)N * 64;          // [N][64] bf16 relu(h1)
    unsigned short* Wt1    = h1 + (size_t)N * 64;              // [(R+1)*64*64]
    unsigned short* Wt2    = Wt1 + (size_t)(R + 1) * 64 * 64;  // [(R+1)*32*64]
    int* gcnt = (int*)(Wt2 + (size_t)(R + 1) * 32 * 64);       // [B]
    int* nrpS = gcnt + B;                                      // [B*64*R]
    int* nrpE = nrpS + (size_t)B * 64 * R;                     // [B*64*R]
    int* rec  = nrpE + (size_t)B * 64 * R;                     // [B*MAXPB]
    int* eidx = rec + (size_t)B * MAXPB;                       // [B*MAXPB]

    const dim3 blk(256);
    const int P  = 512;                       // partition blocks
    const int CH = (E + P - 1) / P;           // 3125 edges per block
    const int n8 = N * 64 / 8;                // 800000

    // ---- Weight pre-transpose + input bf16 cast ----
    transpose_w<64><<<((R + 1) * 64 * 64 + 255) / 256, blk, 0, stream>>>(W1, Ws1, Wt1, R);
    transpose_w<32><<<((R + 1) * 32 * 64 + 255) / 256, blk, 0, stream>>>(W2, Ws2, Wt2, R);
    cast_bf16x8<<<(n8 + 255) / 256, blk, 0, stream>>>(feat, fstage, n8);

    // ---- Build per-(node,rel) CSR (padded buckets) ----
    zero_int<<<(B + 255) / 256, blk, 0, stream>>>(gcnt, B);
    partition_pad<<<P, blk, 0, stream>>>(src, dst, et, gcnt, rec, E, N, B, CH);
    bucket_sort9<<<B, blk, 0, stream>>>(gcnt, rec, eidx, nrpS, nrpE, R);

    // ---- Layer 1: fused aggregate+MFMA -> h1 = relu(.) bf16 ----
    fused_mfma<64, true><<<B, blk, 0, stream>>>(fstage, Wt1, b1, nrpS, nrpE, eidx, h1, N, R);

    // ---- Layer 2: fused aggregate+MFMA -> out fp32 ----
    fused_mfma<32, false><<<B, blk, 0, stream>>>(h1, Wt2, b2, nrpS, nrpE, eidx, out, N, R);
}